// Round 2
// baseline (907.873 us; speedup 1.0000x reference)
//
#include <hip/hip_runtime.h>
#include <hip/hip_bf16.h>
#include <hip/hip_fp8.h>

typedef int i32x8 __attribute__((ext_vector_type(8)));
typedef int i32x4 __attribute__((ext_vector_type(4)));
typedef float f32x4 __attribute__((ext_vector_type(4)));
typedef unsigned char uchar_t;

constexpr int NB = 32768;   // batch rows
constexpr int D1 = 1024;    // K
constexpr int D2 = 4096;    // N
constexpr float BETA_LOG2E = 14.4269504088896340736f; // 10 * log2(e)
constexpr float SCALE_A = 16.0f;        // g1 pre-scale into e4m3 sweet range
constexpr float SCALE_B = 8192.0f;      // dW pre-scale (dW ~ 0.003*N)
constexpr float INV_SCALE = 1.0f / (16.0f * 8192.0f);  // 2^-17

__device__ __forceinline__ uchar_t f32_to_fp8(float f) {
  __hip_fp8_e4m3 q(f);                  // OCP e4m3fn, RNE+satfinite
  return (uchar_t)q.__x;
}

__device__ __forceinline__ void async_copy16(const void* g, void* l) {
  __builtin_amdgcn_global_load_lds(
      (const __attribute__((address_space(1))) void*)g,
      (__attribute__((address_space(3))) void*)l, 16, 0, 0);
}

// ---- 1. fused column stats + normalize + transpose of W ----
// Block handles 64 columns. Pass A: col L2-norm^2 + col sum over all 1024 k.
// Pass B: B8t[j][k] = fp8((W[k][j]*inv - mu[j]) * SCALE_B), LDS-transposed
// so B8t writes are k-coalesced. Replaces colstats+convert_b (no atomics,
// no stats memset). W re-read in pass B is L2-hot (256 KiB/block panel).
__global__ __launch_bounds__(256)
void prep_b(const float* __restrict__ W, uchar_t* __restrict__ B8t,
            float* __restrict__ mu) {
  __shared__ float sqs[4][64], css[4][64];
  __shared__ float sinv[64], smu[64];
  __shared__ float tile[64][65];
  const int t = threadIdx.x;
  const int j0 = blockIdx.x * 64;      // gridDim.x = 64
  const int c = t & 63, g = t >> 6;
  float a = 0.f, b = 0.f;
  const float* wp = W + (size_t)(g * 256) * D2 + j0 + c;
#pragma unroll 8
  for (int k = 0; k < 256; ++k) { float w = wp[(size_t)k * D2]; a += w * w; b += w; }
  sqs[g][c] = a; css[g][c] = b;
  __syncthreads();
  if (t < 64) {
    float sq = sqs[0][t] + sqs[1][t] + sqs[2][t] + sqs[3][t];
    float cs = css[0][t] + css[1][t] + css[2][t] + css[3][t];
    float inv = 1.0f / sqrtf(sq);
    float m = cs * inv * (1.0f / 1024.0f);
    sinv[t] = inv; smu[t] = m; mu[j0 + t] = m;
  }
  __syncthreads();
  const int r4 = t >> 6;
  for (int k0 = 0; k0 < 1024; k0 += 64) {
#pragma unroll
    for (int s = 0; s < 16; ++s) {
      int k = s * 4 + r4;
      tile[k][c] = W[(size_t)(k0 + k) * D2 + j0 + c];
    }
    __syncthreads();
#pragma unroll
    for (int s = 0; s < 16; ++s) {
      int jj = s * 4 + r4;
      float dw = tile[c][jj] * sinv[jj] - smu[jj];
      B8t[(size_t)(j0 + jj) * D1 + k0 + c] = f32_to_fp8(dw * SCALE_B);
    }
    __syncthreads();
  }
}

// ---- 2. g1 fp32 -> fp8 (x16) + row sums. Wave-per-row, grid-stride,
// no __syncthreads/LDS (old version: 128-thr block + block reduce per row).
__global__ __launch_bounds__(256)
void convert_a(const float* __restrict__ g1, uchar_t* __restrict__ A8,
               float* __restrict__ S) {
  const int lane = threadIdx.x & 63;
  const int gw = (blockIdx.x * 256 + threadIdx.x) >> 6;  // 8192 waves
  for (int row = gw; row < NB; row += 8192) {
    const float* src = g1 + (size_t)row * D1 + lane * 16;
    float v[16];
    *(float4*)(v)      = ((const float4*)src)[0];
    *(float4*)(v + 4)  = ((const float4*)src)[1];
    *(float4*)(v + 8)  = ((const float4*)src)[2];
    *(float4*)(v + 12) = ((const float4*)src)[3];
    float sum = 0.f;
    union { uchar_t b[16]; uint4 u; } o;
#pragma unroll
    for (int j = 0; j < 16; ++j) { sum += v[j]; o.b[j] = f32_to_fp8(v[j] * SCALE_A); }
    *(uint4*)(A8 + (size_t)row * D1 + lane * 16) = o.u;
#pragma unroll
    for (int m = 1; m < 64; m <<= 1) sum += __shfl_xor(sum, m, 64);
    if (lane == 0) S[row] = sum;
  }
}

// ---- 3. fused fp8 GEMM + exp-sum, 256x256 tile, 512 thr = 8 waves (2M x 4N),
// per-wave 128x64 out = 8x4 frags of mfma_scale_f32_16x16x128_f8f6f4.
// BK=128 B. LDS 2 x (32K A + 32K B) = 128 KiB, XOR-swizzled (seg^(row&7)),
// staged via global_load_lds with pre-swizzled global source (linear LDS dest).
//
// COUNTED-VMCNT 3-PHASE SCHEDULE (T3+T4): tile staged as 4 units x 2 loads/thr:
//   U_A0 = A rows {0-63,128-191}   (needed by P1: mh=0 frags of both wm groups)
//   U_B0 = B rows {0-31,64-95,128-159,192-223}   (P1: nh=0 cols of all wn)
//   U_B1 = B rows {+32 of each}    (P2: nh=1)
//   U_A1 = A rows {64-127,192-255} (P3: mh=1)
// Next tile's units issue one-per-phase into the dead buffer; waits are
// exact per-wave outstanding-load counts (each thread owns 2 loads/unit):
//   end P1: out = {T.B1,T.A1,T1.A0,T1.B0}=8 -> vmcnt(6) => T.B1 landed
//   end P2: out = {T.A1,T1.A0,T1.B0,T1.B1}=8 -> vmcnt(6) => T.A1 landed
//   end P3: out = {T1 all}=8            -> vmcnt(4) => T1.{A0,B0} landed,
//           4 loads stay IN FLIGHT across the boundary barrier.
// Last tile prefetches tile 0 again (dummy, into dead buffer) so the vmcnt
// literals are iteration-invariant (no branch, no count drift).
// A-frags af[0..3] are reused per mh half; every LDS byte read exactly once.
__global__ __launch_bounds__(512, 2)
void gemm_expsum(const uchar_t* __restrict__ A8, const uchar_t* __restrict__ B8t,
                 const float* __restrict__ S, const float* __restrict__ mu,
                 float* __restrict__ s) {
  __shared__ __align__(16) uchar_t As[2 * 256 * 128];  // 64 KiB
  __shared__ __align__(16) uchar_t Bs[2 * 256 * 128];  // 64 KiB

  const int t = threadIdx.x;
  const int row0 = blockIdx.y * 256;   // gridDim.y = 128
  const int col0 = blockIdx.x * 256;   // gridDim.x = 16 (fast: A-panel L2 reuse)
  const int lane = t & 63;
  const int wave = t >> 6;
  const int wm = (wave >> 2) * 128;    // 2 M-groups
  const int wn = (wave & 3) * 64;      // 4 N-groups
  const int llo = lane & 15, lhi = lane >> 4;

  f32x4 acc[8][4] = {};

  // staging geometry: thread t -> local row r = t>>3, seg = t&7; fetches
  // global segment seg^(r&7) so the LINEAR LDS write lands swizzled.
  // All unit row-offsets are multiples of 8 => swizzle key (row&7) == (r&7).
  const int r   = t >> 3;
  const int rB  = ((r >> 5) << 6) + (r & 31);   // B-unit base rows {0-31,64-95}
  const int seg = t & 7;
  const int swz = seg ^ (r & 7);
  const uchar_t* gA = A8  + (size_t)(row0 + r ) * D1 + swz * 16;
  const uchar_t* gB = B8t + (size_t)(col0 + rB) * D1 + swz * 16;
  uchar_t* lA = As + r  * 128 + seg * 16;
  uchar_t* lB = Bs + rB * 128 + seg * 16;

#define ISSUE_A0(kt, bo) { async_copy16(gA + (kt),              lA + (bo)); \
                           async_copy16(gA + (kt) + 128 * 1024, lA + (bo) + 128 * 128); }
#define ISSUE_B0(kt, bo) { async_copy16(gB + (kt),              lB + (bo)); \
                           async_copy16(gB + (kt) + 128 * 1024, lB + (bo) + 128 * 128); }
#define ISSUE_B1(kt, bo) { async_copy16(gB + (kt) +  32 * 1024, lB + (bo) +  32 * 128); \
                           async_copy16(gB + (kt) + 160 * 1024, lB + (bo) + 160 * 128); }
#define ISSUE_A1(kt, bo) { async_copy16(gA + (kt) +  64 * 1024, lA + (bo) +  64 * 128); \
                           async_copy16(gA + (kt) + 192 * 1024, lA + (bo) + 192 * 128); }

  // lane's fragment k-window lhi*32..+31 = two 16B segs at swizzled slots
  const int sw0 = ((lhi * 2 + 0) ^ (llo & 7)) * 16;
  const int sw1 = ((lhi * 2 + 1) ^ (llo & 7)) * 16;

  // prologue: tile 0 into buf 0 (issue order defines vmcnt age order)
  ISSUE_A0(0, 0); ISSUE_B0(0, 0); ISSUE_B1(0, 0); ISSUE_A1(0, 0);
  asm volatile("s_waitcnt vmcnt(4)" ::: "memory");   // A0,B0 landed; B1,A1 fly
  __builtin_amdgcn_s_barrier();

  for (int T = 0; T < 8; ++T) {
    const int p = T & 1;
    const int kt1 = ((T + 1) & 7) * 128;   // wraps to 0 on last iter (dummy)
    const int bo1 = (p ^ 1) * 32768;
    const uchar_t* baseA = As + p * 32768;
    const uchar_t* baseB = Bs + p * 32768;
    i32x8 af[4], bq[4];

    // ---------- P1: mh=0, nh=0 ----------
    ISSUE_A0(kt1, bo1); ISSUE_B0(kt1, bo1);
#pragma unroll
    for (int q = 0; q < 4; ++q) {
      const uchar_t* a = baseA + (wm + q * 16 + llo) * 128;
      i32x4 h0 = *(const i32x4*)(a + sw0);
      i32x4 h1 = *(const i32x4*)(a + sw1);
      af[q] = __builtin_shufflevector(h0, h1, 0, 1, 2, 3, 4, 5, 6, 7);
    }
#pragma unroll
    for (int j = 0; j < 2; ++j) {
      const uchar_t* b = baseB + (wn + j * 16 + llo) * 128;
      i32x4 h0 = *(const i32x4*)(b + sw0);
      i32x4 h1 = *(const i32x4*)(b + sw1);
      bq[j] = __builtin_shufflevector(h0, h1, 0, 1, 2, 3, 4, 5, 6, 7);
    }
    __builtin_amdgcn_s_setprio(1);
#pragma unroll
    for (int q = 0; q < 4; ++q)
#pragma unroll
      for (int j = 0; j < 2; ++j)
        acc[q][j] = __builtin_amdgcn_mfma_scale_f32_16x16x128_f8f6f4(
            af[q], bq[j], acc[q][j], 0, 0, 0, 127, 0, 127);
    __builtin_amdgcn_s_setprio(0);
    asm volatile("s_waitcnt vmcnt(6)" ::: "memory");  // T.B1 landed
    __builtin_amdgcn_s_barrier();

    // ---------- P2: mh=0, nh=1 ----------
    ISSUE_B1(kt1, bo1);
#pragma unroll
    for (int j = 0; j < 2; ++j) {
      const uchar_t* b = baseB + (wn + (2 + j) * 16 + llo) * 128;
      i32x4 h0 = *(const i32x4*)(b + sw0);
      i32x4 h1 = *(const i32x4*)(b + sw1);
      bq[2 + j] = __builtin_shufflevector(h0, h1, 0, 1, 2, 3, 4, 5, 6, 7);
    }
    __builtin_amdgcn_s_setprio(1);
#pragma unroll
    for (int q = 0; q < 4; ++q)
#pragma unroll
      for (int j = 0; j < 2; ++j)
        acc[q][2 + j] = __builtin_amdgcn_mfma_scale_f32_16x16x128_f8f6f4(
            af[q], bq[2 + j], acc[q][2 + j], 0, 0, 0, 127, 0, 127);
    __builtin_amdgcn_s_setprio(0);
    asm volatile("s_waitcnt vmcnt(6)" ::: "memory");  // T.A1 landed
    __builtin_amdgcn_s_barrier();

    // ---------- P3: mh=1, all nh ----------
    ISSUE_A1(kt1, bo1);
#pragma unroll
    for (int q = 0; q < 4; ++q) {
      const uchar_t* a = baseA + (wm + 64 + q * 16 + llo) * 128;
      i32x4 h0 = *(const i32x4*)(a + sw0);
      i32x4 h1 = *(const i32x4*)(a + sw1);
      af[q] = __builtin_shufflevector(h0, h1, 0, 1, 2, 3, 4, 5, 6, 7);
    }
    __builtin_amdgcn_s_setprio(1);
#pragma unroll
    for (int q = 0; q < 4; ++q)
#pragma unroll
      for (int j = 0; j < 4; ++j)
        acc[4 + q][j] = __builtin_amdgcn_mfma_scale_f32_16x16x128_f8f6f4(
            af[q], bq[j], acc[4 + q][j], 0, 0, 0, 127, 0, 127);
    __builtin_amdgcn_s_setprio(0);
    asm volatile("s_waitcnt vmcnt(4)" ::: "memory");  // T1.{A0,B0} landed; 4 fly
    __builtin_amdgcn_s_barrier();
  }
#undef ISSUE_A0
#undef ISSUE_B0
#undef ISSUE_B1
#undef ISSUE_A1

  // epilogue: x2 = mu_j*S_b + acc*2^-17; per-row sum of exp2(x2*beta*log2e).
  // C/D layout (16x16): col = lane&15, row = (lane>>4)*4 + reg.
  float muv[4];
#pragma unroll
  for (int ni = 0; ni < 4; ++ni) muv[ni] = mu[col0 + wn + ni * 16 + llo];

#pragma unroll
  for (int mi = 0; mi < 8; ++mi) {
    const int row = row0 + wm + mi * 16 + lhi * 4;
    float4 sv = *(const float4*)(S + row);
    float sarr[4] = {sv.x, sv.y, sv.z, sv.w};
    float rs[4];
#pragma unroll
    for (int rr = 0; rr < 4; ++rr) {
      float v = 0.f;
#pragma unroll
      for (int ni = 0; ni < 4; ++ni) {
        float x2 = fmaf(acc[mi][ni][rr], INV_SCALE, muv[ni] * sarr[rr]);
        v += exp2f(x2 * BETA_LOG2E);
      }
      rs[rr] = v;
    }
#pragma unroll
    for (int m = 1; m < 16; m <<= 1) {
#pragma unroll
      for (int rr = 0; rr < 4; ++rr)
        rs[rr] += __shfl_xor(rs[rr], m, 64);
    }
    if (llo == 0) {
#pragma unroll
      for (int rr = 0; rr < 4; ++rr)
        atomicAdd(&s[row + rr], rs[rr]);
    }
  }
}

// ---- 4. out[b] = -(1/beta) * log(s[b]) ----
__global__ void finish_kernel(const float* __restrict__ s, float* __restrict__ out) {
  int b = blockIdx.x * 256 + threadIdx.x;
  out[b] = -0.1f * logf(s[b]);
}

extern "C" void kernel_launch(void* const* d_in, const int* in_sizes, int n_in,
                              void* d_out, int out_size, void* d_ws, size_t ws_size,
                              hipStream_t stream) {
  const float* g1 = (const float*)d_in[0];
  const float* W  = (const float*)d_in[1];
  float* out = (float*)d_out;

  char* ws = (char*)d_ws;
  float* s       = (float*)ws;                    // 32768*4 = 131072
  float* mu      = (float*)(ws + 131072);         // 4096*4
  float* S       = (float*)(ws + 147456);         // 32768*4
  uchar_t* A8    = (uchar_t*)(ws + 278528);       // 32 MiB
  uchar_t* B8t   = (uchar_t*)(ws + 278528 + 33554432);  // 4 MiB

  hipMemsetAsync(ws, 0, 131072, stream);  // zero s only

  prep_b<<<dim3(64), 256, 0, stream>>>(W, B8t, mu);
  convert_a<<<dim3(2048), 256, 0, stream>>>(g1, A8, S);
  gemm_expsum<<<dim3(16, 128), 512, 0, stream>>>(A8, B8t, S, mu, s);
  finish_kernel<<<dim3(128), 256, 0, stream>>>(s, out);
}